// Round 12
// baseline (514.019 us; speedup 1.0000x reference)
//
#include <hip/hip_runtime.h>
#include <stdint.h>

// ---------- sizes (fixed by setup_inputs) ----------
#define BATCH   65536
#define FIN     32        // layer-1 in
#define HID     64        // layer-1 out / layer-2 in
#define NOUT    2048      // layer-2 out
#define NC      8         // bases per element
#define NF      9         // features per element (silu + 8 bases)
#define K1      288       // FIN*NF
#define K2      576       // HID*NF

typedef __bf16 bf16x8 __attribute__((ext_vector_type(8)));
typedef float f32x4  __attribute__((ext_vector_type(4)));
typedef float f32x16 __attribute__((ext_vector_type(16)));

// ---------- helpers ----------
__device__ __forceinline__ uint16_t f2bf(float f) {
    uint32_t u = __builtin_bit_cast(uint32_t, f);
    uint32_t r = (u + 0x7fffu + ((u >> 16) & 1u)) >> 16;
    return (uint16_t)r;
}
__device__ __forceinline__ float silu_f(float v) {
    return v / (1.f + __expf(-v));
}

// Closed-form uniform cubic B-spline bases. Knots g[t]=(t-3)*0.4-1, t=0..11.
__device__ __forceinline__ void bspline8u(float xv, float out[8]) {
    float s = (xv + 2.2f) * 2.5f;
    int c = (int)floorf(s);
    float gc = (float)(c - 3) * 0.4f - 1.0f;
    float u = (xv - gc) * 2.5f;
    float u1 = 1.f - u;
    float uu = u * u, u3 = uu * u;
    float w0 = u1 * u1 * u1 * (1.f / 6.f);
    float w1 = (3.f * u3 - 6.f * uu + 4.f) * (1.f / 6.f);
    float w2 = (-3.f * u3 + 3.f * uu + 3.f * u + 1.f) * (1.f / 6.f);
    float w3 = u3 * (1.f / 6.f);
#pragma unroll
    for (int t = 0; t < 8; t++) {
        int d = c - t;
        out[t] = (d == 0) ? w3 : (d == 1) ? w2 : (d == 2) ? w1 : (d == 3) ? w0 : 0.f;
    }
}

// ---------- pack kernels ----------
// W1L[o][k] bf16, k = i*9 + j (j=0 silu, 1..8 bases), compact [64][288]
__global__ void pack_w1(const float* __restrict__ bw1, const float* __restrict__ sw1,
                        const float* __restrict__ ss1, uint16_t* __restrict__ w1L) {
    int idx = blockIdx.x * 256 + threadIdx.x;
    if (idx >= 64 * K1) return;
    int o = idx / K1, k = idx % K1;
    int i = k / 9, j = k % 9;
    float v = (j == 0) ? bw1[o * FIN + i]
                       : sw1[(o * FIN + i) * NC + (j - 1)] * ss1[o * FIN + i];
    w1L[idx] = f2bf(v);
}

// W2 k-major-8: w2km[slot][n][e] with slot=k>>3, e=k&7, k-order = j*64+i.
// Writes are idx-linear (coalesced). 72*2048*8 = 1,179,648 elems.
__global__ void pack_w2km(const float* __restrict__ bw2, const float* __restrict__ sw2,
                          const float* __restrict__ ss2, uint16_t* __restrict__ w2km) {
    int idx = blockIdx.x * 256 + threadIdx.x;     // slot*16384 + n*8 + e
    int slot = idx >> 14;
    int n = (idx >> 3) & 2047;
    int e = idx & 7;
    int k = slot * 8 + e;
    int j = k >> 6, i = k & 63;
    float v = (j == 0) ? bw2[n * HID + i]
                       : sw2[(n * HID + i) * NC + (j - 1)] * ss2[n * HID + i];
    w2km[idx] = f2bf(v);
}

// ---------- fused megakernel: LN + KAN1 + featurize2 (LDS) + KAN2 GEMM ----------
// One block = 128 batch rows, 512 threads (8 waves). LDS (144 KiB):
//   phase A: W1 [64][296] @0 (37,888 B) + A1 [128][296] @37,888 (75,776 B)
//   phase B: A2 k-major [72 slots][128 rows][8 elems] bf16 @0 (147,456 B),
//            aliasing the dead phase-A scratch.
// GEMM phase is BARRIER-FREE: A-frags from resident LDS (contiguous 512 B
// per 32-lane group -> conflict-free), B-frags global->VGPR from k-major W2
// (L2-resident, 512 B coalesced), each wave owns cols [wv*256, wv*256+256).
#define A1LD   296
__global__ __launch_bounds__(512, 2) void kan_fused(
    const float* __restrict__ x, const float* __restrict__ lnw, const float* __restrict__ lnb,
    const uint16_t* __restrict__ w1L, const uint16_t* __restrict__ w2km,
    float* __restrict__ C) {

    __shared__ __align__(16) char fsm[147456];
    uint16_t* w1s = (uint16_t*)fsm;              // [64][296]
    uint16_t* a1s = (uint16_t*)(fsm + 37888);    // [128][296]
    const char* a2kb = fsm;                      // [72][128][8] bf16 (phase B)

    const int tid = threadIdx.x;
    const int wv = tid >> 6, lane = tid & 63;
    const int rowBase = blockIdx.x * 128;

    // ---- stage W1 [64][288] -> [64][296] ----
    for (int i = tid; i < 2304; i += 512) {
        int o = i / 36, cc = i % 36;
        uint4 v = *(const uint4*)(w1L + i * 8);
        *(uint4*)&w1s[o * A1LD + cc * 8] = v;
    }

    // ---- phase 1: LN + featurize x (4 threads/row, 8 inputs each) ----
    const int prow = tid >> 2, pq = tid & 3;
    const float* xp = x + (size_t)(rowBase + prow) * FIN + pq * 8;
    float xv[8];
    *(float4*)&xv[0] = ((const float4*)xp)[0];
    *(float4*)&xv[4] = ((const float4*)xp)[1];
    float s = 0.f, s2v = 0.f;
#pragma unroll
    for (int j = 0; j < 8; j++) { s += xv[j]; s2v += xv[j] * xv[j]; }
    s += __shfl_xor(s, 1);  s2v += __shfl_xor(s2v, 1);
    s += __shfl_xor(s, 2);  s2v += __shfl_xor(s2v, 2);
    const float mu = s * (1.f / 32.f);
    const float var = s2v * (1.f / 32.f) - mu * mu;
    const float rstd = rsqrtf(var + 1e-5f);

    float wl[8], bl[8];
    *(float4*)&wl[0] = ((const float4*)(lnw + pq * 8))[0];
    *(float4*)&wl[4] = ((const float4*)(lnw + pq * 8))[1];
    *(float4*)&bl[0] = ((const float4*)(lnb + pq * 8))[0];
    *(float4*)&bl[4] = ((const float4*)(lnb + pq * 8))[1];

    __align__(16) uint16_t tmp[72];
#pragma unroll
    for (int ii = 0; ii < 8; ii++) {
        float xn = (xv[ii] - mu) * rstd * wl[ii] + bl[ii];
        tmp[ii * 9] = f2bf(silu_f(xn));
        float bs[8];
        bspline8u(xn, bs);
#pragma unroll
        for (int j = 0; j < 8; j++) tmp[ii * 9 + 1 + j] = f2bf(bs[j]);
    }
    {
        uint16_t* dst = &a1s[prow * A1LD + pq * 72];
#pragma unroll
        for (int q = 0; q < 9; q++) *(uint4*)(dst + q * 8) = *(const uint4*)&tmp[q * 8];
    }
    __syncthreads();

    // ---- phase 2: h = A1 x W1 via MFMA; wave wv owns rows wv*16..+15 ----
    f32x4 acc1[4];
#pragma unroll
    for (int n = 0; n < 4; n++) acc1[n] = (f32x4){0.f, 0.f, 0.f, 0.f};
    const int arow = wv * 16 + (lane & 15);
    const int koff = (lane >> 4) * 8;
#pragma unroll
    for (int ks = 0; ks < 9; ++ks) {
        bf16x8 af = *(const bf16x8*)&a1s[arow * A1LD + ks * 32 + koff];
#pragma unroll
        for (int n = 0; n < 4; n++) {
            bf16x8 bv = *(const bf16x8*)&w1s[(n * 16 + (lane & 15)) * A1LD + ks * 32 + koff];
            acc1[n] = __builtin_amdgcn_mfma_f32_16x16x32_bf16(af, bv, acc1[n], 0, 0, 0);
        }
    }
    __syncthreads();   // W1/A1 dead; A2 region aliases them

    // ---- phase 3: featurize h -> A2 k-major LDS [slot][row][8] ----
    {
        const int r0 = wv * 16 + ((lane >> 4) << 2);
        const int cb = lane & 15;
        uint16_t* a2w = (uint16_t*)fsm;
#pragma unroll
        for (int n = 0; n < 4; n++)
#pragma unroll
            for (int r = 0; r < 4; r++) {
                float h = acc1[n][r];
                float o9[9];
                o9[0] = silu_f(h);
                bspline8u(h, &o9[1]);
#pragma unroll
                for (int j = 0; j < 9; j++) {
                    int c = n * 16 + cb + j * 64;             // k index
                    a2w[(c >> 3) * 1024 + (r0 + r) * 8 + (c & 7)] = f2bf(o9[j]);
                }
            }
    }
    __syncthreads();

    // ---- phase 4: barrier-free GEMM. wave wv -> cols [wv*256, +256) ----
    // A frag (step s∈[0,36), m∈[0,4)): lane row=lane&31, k=s*16+(lane>>5)*8+e
    //   byte = (s*2 + (lane>>5))*2048 + (m*32 + (lane&31))*16
    // B frag (step s, nf): col = wv*256 + nf*32 + (lane&31)
    //   byte = (s*2 + (lane>>5))*32768 + col*16
    const int r5 = lane & 31, kg = lane >> 5;
    const char* aB = a2kb + kg * 2048 + r5 * 16;
    const char* bB = (const char*)w2km + kg * 32768 + (wv * 256 + r5) * 16;

#define LOADB(G, g, nfo) do { _Pragma("unroll") \
    for (int ss = 0; ss < 4; ++ss) \
        G[ss] = *(const bf16x8*)(bB + (nfo) + (size_t)((g) * 4 + ss) * 65536); } while (0)

#define COMP4(G, g) do { _Pragma("unroll") \
    for (int ss = 0; ss < 4; ++ss) { \
        const char* ap = aB + (size_t)((g) * 4 + ss) * 4096; \
        bf16x8 am0 = *(const bf16x8*)(ap); \
        bf16x8 am1 = *(const bf16x8*)(ap + 512); \
        bf16x8 am2 = *(const bf16x8*)(ap + 1024); \
        bf16x8 am3 = *(const bf16x8*)(ap + 1536); \
        acc[0] = __builtin_amdgcn_mfma_f32_32x32x16_bf16(am0, G[ss], acc[0], 0, 0, 0); \
        acc[1] = __builtin_amdgcn_mfma_f32_32x32x16_bf16(am1, G[ss], acc[1], 0, 0, 0); \
        acc[2] = __builtin_amdgcn_mfma_f32_32x32x16_bf16(am2, G[ss], acc[2], 0, 0, 0); \
        acc[3] = __builtin_amdgcn_mfma_f32_32x32x16_bf16(am3, G[ss], acc[3], 0, 0, 0); \
    } } while (0)

#pragma unroll
    for (int nf = 0; nf < 8; ++nf) {
        const int nfo = nf * 512;
        f32x16 acc[4];
#pragma unroll
        for (int m = 0; m < 4; m++)
#pragma unroll
            for (int r = 0; r < 16; r++) acc[m][r] = 0.f;

        bf16x8 B0[4], B1[4], B2[4];
        LOADB(B0, 0, nfo); LOADB(B1, 1, nfo);
        LOADB(B2, 2, nfo); COMP4(B0, 0);
        LOADB(B0, 3, nfo); COMP4(B1, 1);
        LOADB(B1, 4, nfo); COMP4(B2, 2);
        LOADB(B2, 5, nfo); COMP4(B0, 3);
        LOADB(B0, 6, nfo); COMP4(B1, 4);
        LOADB(B1, 7, nfo); COMP4(B2, 5);
        LOADB(B2, 8, nfo); COMP4(B0, 6);
        COMP4(B1, 7);
        COMP4(B2, 8);

        // C/D layout (verified r11): col=lane&31, row=(r&3)+8*(r>>2)+4*kg
        const int colA = wv * 256 + nf * 32 + r5;
        const int crow = rowBase + 4 * kg;
#pragma unroll
        for (int m = 0; m < 4; ++m) {
            float* cp = C + (size_t)(crow + m * 32) * NOUT + colA;
#pragma unroll
            for (int r = 0; r < 16; ++r)
                cp[(size_t)((r & 3) + 8 * (r >> 2)) * NOUT] = acc[m][r];
        }
    }
#undef LOADB
#undef COMP4
}

// ---------- launcher ----------
extern "C" void kernel_launch(void* const* d_in, const int* in_sizes, int n_in,
                              void* d_out, int out_size, void* d_ws, size_t ws_size,
                              hipStream_t stream) {
    const float* x    = (const float*)d_in[0];
    const float* lnw  = (const float*)d_in[1];
    const float* lnb  = (const float*)d_in[2];
    const float* bw1  = (const float*)d_in[3];
    const float* sw1  = (const float*)d_in[4];
    const float* ss1  = (const float*)d_in[5];
    const float* bw2  = (const float*)d_in[6];
    const float* sw2  = (const float*)d_in[7];
    const float* ss2  = (const float*)d_in[8];

    char* ws = (char*)d_ws;
    uint16_t* w1L  = (uint16_t*)ws;                 // 36,864 B
    uint16_t* w2km = (uint16_t*)(ws + 65536);       // 2,359,296 B
    float* out = (float*)d_out;

    pack_w1<<<dim3(72), dim3(256), 0, stream>>>(bw1, sw1, ss1, w1L);
    pack_w2km<<<dim3(4608), dim3(256), 0, stream>>>(bw2, sw2, ss2, w2km);
    kan_fused<<<dim3(BATCH / 128), dim3(512), 0, stream>>>(x, lnw, lnb, w1L, w2km, out);
}